// Round 14
// baseline (1056.667 us; speedup 1.0000x reference)
//
#include <hip/hip_runtime.h>
#include <math.h>

#define NN 20000
#define GG 8
#define NPG 2500
#define EE 640000
#define EPAD 944000   // upper bound: E + 15*NN, per-node degree padded to mult of 16
#define NLAYERS 3
#define CUTR 6.0f
#define AVGN 32.0f
#define NBASIS 8
#define NT 4096       // radial-table intervals over r in [0,1]; 4097 entries/layer

// Hard per-wave LDS handoff (used only in k_sortrows now): drain the DS queue so
// prior ds ops are COMPLETE; sched_barrier pins the compiler.
#define LDS_HANDOFF() do { \
    asm volatile("s_waitcnt lgkmcnt(0)" ::: "memory"); \
    __builtin_amdgcn_sched_barrier(0); \
  } while (0)

__device__ __forceinline__ float silu_f(float x){ return x / (1.0f + __expf(-x)); }

// ---------------- CSR degree count ----------------
__global__ void k_count(const int* __restrict__ ei, int* __restrict__ deg)
{
  int e = blockIdx.x * 256 + threadIdx.x;
  if (e >= EE) return;
  atomicAdd(&deg[ei[EE + e]], 1);
}

// padded scan: each row's extent rounded up to multiple of 16 (tiles never cross nodes)
__global__ void k_scan(const int* __restrict__ deg, int* __restrict__ rowptrP,
                       int* __restrict__ cursor)
{
  __shared__ int buf[1024];
  __shared__ int carry;
  int tid = threadIdx.x;
  if (tid == 0) carry = 0;
  __syncthreads();
  for (int base = 0; base < NN; base += 1024) {
    int i = base + tid;
    int x = (i < NN) ? ((deg[i] + 15) & ~15) : 0;
    buf[tid] = x; __syncthreads();
    for (int off = 1; off < 1024; off <<= 1) {
      int t = (tid >= off) ? buf[tid - off] : 0;
      __syncthreads();
      buf[tid] += t;
      __syncthreads();
    }
    int incl = buf[tid];
    int c = carry;
    __syncthreads();
    if (i < NN) { rowptrP[i] = c + incl - x; cursor[i] = c + incl - x; }
    if (tid == 1023) carry = c + incl;
    __syncthreads();
  }
  if (tid == 0) rowptrP[NN] = carry;
}

// ---------------- scatter edge ids into padded CSR slots (perm nondeterministic) ----------------
__global__ void k_scatter(const int* __restrict__ ei, int* __restrict__ cursor,
                          unsigned* __restrict__ csrE)
{
  int e = blockIdx.x * 256 + threadIdx.x;
  if (e >= EE) return;
  int slot = atomicAdd(&cursor[ei[EE + e]], 1);
  csrE[slot] = (unsigned)e;
}

// ---------------- per-row sort by edge id -> DETERMINISTIC slot assignment ----------------
__global__ __launch_bounds__(512) void k_sortrows(const int* __restrict__ rowptrP,
                                                  unsigned* __restrict__ csrE)
{
  __shared__ unsigned buf[8*512];
  int w = threadIdx.x >> 6, lane = threadIdx.x & 63;
  unsigned* b = buf + w*512;
  int r = blockIdx.x*8 + w;
  int start = rowptrP[r], end = rowptrP[r+1];
  int P = end - start;
  if (P < 2 || P > 512) return;   // max padded degree << 512 for this input
  for (int i = lane; i < P; i += 64) b[i] = csrE[start + i];
  LDS_HANDOFF();                 // loads committed before pass-0 cross-lane reads
  for (int pass = 0; pass < P; ++pass) {
    int par = pass & 1;
    for (int i = lane; 2*i + par + 1 < P; i += 64) {
      int idx = 2*i + par;
      unsigned a = b[idx], c = b[idx+1];
      if (a > c) { b[idx] = c; b[idx+1] = a; }
    }
    LDS_HANDOFF();               // pass-p ops complete before pass-p+1 touches buf
  }
  for (int i = lane; i < P; i += 64) csrE[start + i] = b[i];
}

// ---------------- geometry per SLOT ----------------
// y1m.w encodes BOTH mask and table coordinate: w = mask ? min(r,1) : -1.
// Pads and zero-length edges get w = -1 (gather treats w<0 as mask 0).
__global__ void k_geom_slot(const float* __restrict__ pos, const float* __restrict__ cell,
                            const float* __restrict__ Sij, const int* __restrict__ ei,
                            const int* __restrict__ batch, const unsigned* __restrict__ csrE,
                            float* __restrict__ y1mP, int* __restrict__ sndP)
{
  int slot = blockIdx.x * 256 + threadIdx.x;
  if (slot >= EPAD) return;
  int e = (int)csrE[slot];
  if (e < 0) {
    ((float4*)y1mP)[slot] = make_float4(0.0f, 0.0f, 0.0f, -1.0f);
    sndP[slot] = 0;
    return;
  }
  int snd = ei[e], rcv = ei[EE + e];
  int g = batch[snd];
  float s0 = Sij[e*3+0], s1 = Sij[e*3+1], s2_ = Sij[e*3+2];
  const float* cg = cell + g*9;
  float R[3];
  #pragma unroll
  for (int j = 0; j < 3; ++j) {
    float shift = s0*cg[0*3+j] + s1*cg[1*3+j] + s2_*cg[2*3+j];
    R[j] = (pos[rcv*3+j] - pos[snd*3+j] + shift) * (1.0f/CUTR);
  }
  float len = sqrtf(R[0]*R[0] + R[1]*R[1] + R[2]*R[2]);
  float safe = (len > 0.0f) ? len : 1.0f;
  float inv  = 1.0f / safe;
  const float sqrt3 = 1.7320508075688772f;
  float rq = (len > 0.0f) ? fminf(len, 1.0f) : -1.0f;   // table coord or mask=0
  ((float4*)y1mP)[slot] = make_float4(sqrt3*R[0]*inv, sqrt3*R[1]*inv, sqrt3*R[2]*inv, rq);
  sndP[slot] = snd;
}

// ---------------- radial table build: T[l][ip][c] = float4(paths 0..3), f32 ----------------
// wts = MLP(bess(r)*env(r)) depends on ONE scalar r; tabulate at 4097 points in f32.
// For r>=1 features are exactly 0 (env=0) -> F constant = MLP(0) = T[NT]; gather clamps.
// Lerp error ~ h^2|F''|/8 ~ 1e-5 relative (r10/r13 measured: absmax 0.0).
__global__ __launch_bounds__(64) void k_tab(const float* __restrict__ Wr1, const float* __restrict__ br1,
                                            const float* __restrict__ Wr2, const float* __restrict__ br2,
                                            const float* __restrict__ Wr3, float4* __restrict__ Twts)
{
  __shared__ float h1s[64], h2s[64];
  int l  = blockIdx.x / (NT+1);
  int ip = blockIdx.x - l*(NT+1);
  int c  = threadIdx.x;
  float r  = (float)ip / (float)NT;
  float re = fmaxf(r, 1e-7f);
  float env = (r < 1.0f) ? (1.0f - 6.0f*r*r + 8.0f*r*r*r - 3.0f*r*r*r*r) : 0.0f;
  const float sqrt2 = 1.4142135623730951f;
  const float PI_F = 3.14159265358979323846f;
  float ef[NBASIS];
  #pragma unroll
  for (int n = 1; n <= NBASIS; ++n)
    ef[n-1] = sqrt2 * sinf(PI_F * (float)n * re) / re * env;
  float a = br1[l*64 + c];
  #pragma unroll
  for (int k = 0; k < NBASIS; ++k) a += ef[k] * Wr1[l*512 + k*64 + c];
  h1s[c] = a / (1.0f + expf(-a));
  __syncthreads();
  float b = br2[l*64 + c];
  for (int k = 0; k < 64; ++k) b += h1s[k] * Wr2[l*4096 + k*64 + c];
  h2s[c] = b / (1.0f + expf(-b));
  __syncthreads();
  float acc0 = 0, acc1 = 0, acc2 = 0, acc3 = 0;
  for (int k = 0; k < 64; ++k) {
    float h = h2s[k];
    const float* wv = Wr3 + l*16384 + k*256;   // wts[:,p,c] = flat[p*64 + c]
    acc0 += h * wv[0*64 + c];
    acc1 += h * wv[1*64 + c];
    acc2 += h * wv[2*64 + c];
    acc3 += h * wv[3*64 + c];
  }
  Twts[(size_t)(l*(NT+1) + ip)*64 + c] = make_float4(acc0, acc1, acc2, acc3);
}

// ---------------- embed: s, nodeP (layer-0 up), xf table, v/acc_out zero-init ----------------
__global__ void k_embed0(const int* __restrict__ species, const float* __restrict__ W_embed,
                         const float* __restrict__ W_x, const float* __restrict__ Wus0,
                         float* __restrict__ T,
                         float* __restrict__ s, float* __restrict__ v,
                         float4* __restrict__ nodeP, float* __restrict__ acc_out)
{
  if (blockIdx.x == 0) {        // xf table (512 entries), used by k_post every layer
    for (int t = threadIdx.x; t < 512; t += 256) {
      int sp = t >> 6, o = t & 63;
      float a = 0.0f;
      for (int k = 0; k < 64; ++k) a += W_embed[sp*64 + k] * W_x[k*64 + o];
      T[t] = a;
    }
  }
  int gid = blockIdx.x * 256 + threadIdx.x;
  if (gid >= NN * 64) return;
  int n = gid >> 6, c = gid & 63;
  int sp = species[n];
  s[gid] = W_embed[sp*64 + c];
  float up = 0.0f;              // layer-0 s_up inline (v=0 so v_up=0)
  for (int k = 0; k < 64; ++k) up += W_embed[sp*64 + k] * Wus0[k*64 + c];
  nodeP[gid] = make_float4(up, 0.0f, 0.0f, 0.0f);
  #pragma unroll
  for (int m = 0; m < 3; ++m) v[(n*3 + m)*64 + c] = 0.0f;
  if (c < 9) acc_out[n*9 + c] = 0.0f;
}

// ---------------- gather: table-lerp radial weights + message paths + aggregation ----------------
// GEOMETRY = r10's proven best (8-wave 512-thread blocks, 2504 blocks, Occ 17.4%,
// 119us/layer). r13 measured 1-wave blocks WORSE (dispatch-granularity: Occ 10.4%).
// THIS ROUND: delete the LDS staging entirely. Each lane loads its quad's 4 edges
// DIRECTLY (same-address across the quad's 16 lanes -> hardware broadcast, L1-hit).
// Zero DS ops, zero fences, zero sched_barriers -> the compiler can software-pipeline
// tiles freely (the two per-tile lgkmcnt(0) drains were serializing the loop).
// Same math, same accumulation order -> bitwise-identical output (absmax 0.0).
// XCD swizzle: graph = blockIdx%8 -> graph's nodeP slice (2.5MB) lives in that XCD L2.
__global__ __launch_bounds__(512) void k_gather(
    const int* __restrict__ rowptrP,
    const float4* __restrict__ y1mP, const int* __restrict__ sndP,
    const float4* __restrict__ nodeP, const float4* __restrict__ Twts,
    float4* __restrict__ aggP)
{
  int tid = threadIdx.x;
  int w = tid >> 6, lane = tid & 63;
  int n16 = lane & 15, quad = lane >> 4;
  // XCD swizzle: graph = blockIdx%8, node-within-graph = (blockIdx/8)*8 + wave
  int g = blockIdx.x & 7, rr = (blockIdx.x >> 3)*8 + w;
  if (rr < NPG) {
  int r = g*NPG + rr;
  int start = rowptrP[r], end = rowptrP[r+1];
  float as[4] = {0,0,0,0};
  float av[4][3] = {{0,0,0},{0,0,0},{0,0,0},{0,0,0}};
  const float inv_sqrt3 = 0.5773502691896258f;

  for (int e0 = start; e0 < end; e0 += 16) {
    int eq = e0 + quad*4;
    // direct per-quad edge loads (same addr across 16 lanes -> broadcast)
    float4 yj[4]; int sj[4];
    #pragma unroll
    for (int j = 0; j < 4; ++j) {
      yj[j] = y1mP[eq + j];
      sj[j] = sndP[eq + j];
    }
    float mkj[4], fracj[4]; int idxj[4];
    #pragma unroll
    for (int j = 0; j < 4; ++j) {
      float u = yj[j].w;
      mkj[j] = (u >= 0.0f) ? 1.0f : 0.0f;
      float ppos = fmaxf(u, 0.0f) * (float)NT;
      int idx = (int)ppos; if (idx > NT-1) idx = NT-1;
      idxj[j] = idx;
      fracj[j] = ppos - (float)idx;
    }
    // sender rows (per-lane distinct via n16; latency overlaps table loads)
    float4 np[4][4];
    #pragma unroll
    for (int ctm = 0; ctm < 4; ++ctm)
      #pragma unroll
      for (int j = 0; j < 4; ++j)
        np[ctm][j] = nodeP[(size_t)sj[j]*64 + ctm*16 + n16];
    // message paths: wts from table lerp (coalesced: 16 lanes x consecutive float4)
    #pragma unroll
    for (int ctm = 0; ctm < 4; ++ctm) {
      #pragma unroll
      for (int j = 0; j < 4; ++j) {
        const float4* tp = Twts + (size_t)idxj[j]*64 + ctm*16 + n16;
        float4 t0 = tp[0];
        float4 t1 = tp[64];
        float f = fracj[j], mk = mkj[j];
        float4 wp;
        wp.x = mk*(t0.x + f*(t1.x - t0.x));
        wp.y = mk*(t0.y + f*(t1.y - t0.y));
        wp.z = mk*(t0.z + f*(t1.z - t0.z));
        wp.w = mk*(t0.w + f*(t1.w - t0.w));
        float4 y = yj[j];
        float4 npv = np[ctm][j];
        float dot = npv.y*y.x + npv.z*y.y + npv.w*y.z;
        float t2 = wp.z*npv.x;
        as[ctm]    += wp.x*npv.x + wp.y*dot*inv_sqrt3;
        av[ctm][0] += t2*y.x + wp.w*npv.y;
        av[ctm][1] += t2*y.y + wp.w*npv.z;
        av[ctm][2] += t2*y.z + wp.w*npv.w;
      }
    }
  }
  // cross-quad butterfly + write packed agg
  const float invavg = 1.0f / AVGN;
  #pragma unroll
  for (int ctm = 0; ctm < 4; ++ctm) {
    float v0 = as[ctm], v1 = av[ctm][0], v2 = av[ctm][1], v3 = av[ctm][2];
    v0 += __shfl_xor(v0, 16); v0 += __shfl_xor(v0, 32);
    v1 += __shfl_xor(v1, 16); v1 += __shfl_xor(v1, 32);
    v2 += __shfl_xor(v2, 16); v2 += __shfl_xor(v2, 32);
    v3 += __shfl_xor(v3, 16); v3 += __shfl_xor(v3, 32);
    if (quad == 0)
      aggP[(size_t)r*64 + ctm*16 + n16] =
          make_float4(v0*invavg, v1*invavg, v2*invavg, v3*invavg);
  }
  }  // rr < NPG
}

// ---------------- post: msg/sc/product + readout + NEXT layer's up-projection ----------------
// 1 node/wave, 32 KB LDS -> 4 blocks/CU (32 waves). L2-streamed weights.
// Block-uniform control flow -> real __syncthreads() at the three cross-lane handoffs.
__global__ __launch_bounds__(512) void k_post(
    const float4* __restrict__ aggP, const int* __restrict__ species,
    const float* __restrict__ T,
    float* __restrict__ s, float* __restrict__ v,
    const float* __restrict__ Wms, const float* __restrict__ Wmv,
    const float* __restrict__ Wscs, const float* __restrict__ Wscv,
    const float* __restrict__ Wps, const float* __restrict__ Wpv,
    const float* __restrict__ Wread,
    const float* __restrict__ Wus_n, const float* __restrict__ Wuv_n,
    float4* __restrict__ nodeP, float* __restrict__ acc_out, int has_next)
{
  __shared__ float lds[8*1024];
  int tid = threadIdx.x; int w = tid >> 6, c = tid & 63;
  float* asb = lds + w*1024;   // 64
  float* avb = asb + 64;       // 192
  float* sob = avb + 192;      // 64
  float* vob = sob + 64;       // 192
  float* tsb = vob + 192;      // 64
  float* tvb = tsb + 64;       // 192
  float* snb = tvb + 192;      // 64
  float* vnb = snb + 64;       // 192
  int n = blockIdx.x*8 + w;
  int sp = species[n];
  float4 ag = aggP[(size_t)n*64 + c];
  asb[c] = ag.x; avb[c] = ag.y; avb[64+c] = ag.z; avb[128+c] = ag.w;
  sob[c] = s[n*64 + c];
  #pragma unroll
  for (int m = 0; m < 3; ++m) vob[m*64 + c] = v[(n*3 + m)*64 + c];
  __syncthreads();             // phase-1 writes -> cross-lane reads
  float ms = 0, mv0 = 0, mv1 = 0, mv2 = 0;
  for (int k = 0; k < 64; ++k) {
    float wm = Wms[k*64 + c];
    ms  += asb[k]*wm;
    float wv = Wmv[k*64 + c];
    mv0 += avb[k]*wv; mv1 += avb[64+k]*wv; mv2 += avb[128+k]*wv;
  }
  float xf = T[sp*64 + c];
  tsb[c] = xf*ms; tvb[c] = xf*mv0; tvb[64+c] = xf*mv1; tvb[128+c] = xf*mv2;
  __syncthreads();             // phase-2 writes -> cross-lane reads
  const float* Wss = Wscs + sp*4096;
  const float* Wsv = Wscv + sp*4096;
  float sn_ = 0, vn0 = 0, vn1 = 0, vn2 = 0;
  for (int k = 0; k < 64; ++k) {
    float wp  = Wps[k*64 + c];  sn_ += tsb[k]*wp;
    float wsc = Wss[k*64 + c];  sn_ += sob[k]*wsc;
    float wpv = Wpv[k*64 + c];
    vn0 += tvb[k]*wpv; vn1 += tvb[64+k]*wpv; vn2 += tvb[128+k]*wpv;
    float wsv = Wsv[k*64 + c];
    vn0 += vob[k]*wsv; vn1 += vob[64+k]*wsv; vn2 += vob[128+k]*wsv;
  }
  s[n*64 + c] = sn_;
  v[(n*3+0)*64 + c] = vn0; v[(n*3+1)*64 + c] = vn1; v[(n*3+2)*64 + c] = vn2;
  snb[c] = sn_; vnb[c] = vn0; vnb[64+c] = vn1; vnb[128+c] = vn2;
  __syncthreads();             // phase-3 writes -> cross-lane reads
  if (c < 9) {                         // readout, silu-accumulated across layers
    int o3 = c / 3, m = c % 3;
    const float* wr = Wread + o3*64;
    float a = 0.0f;
    for (int k = 0; k < 64; ++k) a += vnb[m*64 + k]*wr[k];
    acc_out[n*9 + c] += silu_f(a);
  }
  if (has_next) {                      // fused up-projection for next layer
    float su = 0, u0 = 0, u1 = 0, u2 = 0;
    for (int k = 0; k < 64; ++k) {
      float wu = Wus_n[k*64 + c]; su += snb[k]*wu;
      float wv = Wuv_n[k*64 + c];
      u0 += vnb[k]*wv; u1 += vnb[64+k]*wv; u2 += vnb[128+k]*wv;
    }
    nodeP[(size_t)n*64 + c] = make_float4(su, u0, u1, u2);
  }
}

// ---------------- final graph reduction ----------------
__global__ void k_final(const float* __restrict__ acc_out, float* __restrict__ out)
{
  __shared__ float red[256];
  int g = blockIdx.x / 9, j = blockIdx.x % 9;
  int tid = threadIdx.x;
  float a = 0.0f;
  for (int n = g*NPG + tid; n < (g + 1)*NPG; n += 256) a += acc_out[n*9 + j];
  red[tid] = a; __syncthreads();
  for (int off = 128; off > 0; off >>= 1) {
    if (tid < off) red[tid] += red[tid + off];
    __syncthreads();
  }
  if (tid == 0) out[g*9 + j] = red[0];
}

extern "C" void kernel_launch(void* const* d_in, const int* in_sizes, int n_in,
                              void* d_out, int out_size, void* d_ws, size_t ws_size,
                              hipStream_t stream)
{
  const float* pos     = (const float*)d_in[0];
  const float* cell    = (const float*)d_in[1];
  const float* Sij     = (const float*)d_in[2];
  const float* W_embed = (const float*)d_in[3];
  const float* W_x     = (const float*)d_in[4];
  const float* W_up_s  = (const float*)d_in[5];
  const float* W_up_v  = (const float*)d_in[6];
  const float* Wr1     = (const float*)d_in[7];
  const float* br1     = (const float*)d_in[8];
  const float* Wr2     = (const float*)d_in[9];
  const float* br2     = (const float*)d_in[10];
  const float* Wr3     = (const float*)d_in[11];
  const float* W_msg_s = (const float*)d_in[12];
  const float* W_msg_v = (const float*)d_in[13];
  const float* W_sc_s  = (const float*)d_in[14];
  const float* W_sc_v  = (const float*)d_in[15];
  const float* W_p_s   = (const float*)d_in[16];
  const float* W_p_v   = (const float*)d_in[17];
  const float* W_read  = (const float*)d_in[18];
  const int*   ei      = (const int*)d_in[19];
  const int*   batch   = (const int*)d_in[20];
  const int*   species = (const int*)d_in[21];
  float* out = (float*)d_out;

  char* ws = (char*)d_ws;
  size_t off = 0;
  auto alloc = [&](size_t bytes) -> void* {
    void* p = ws + off;
    off += (bytes + 255) & ~(size_t)255;
    return p;
  };
  float* y1mP    = (float*)alloc((size_t)EPAD*4*4);
  int*   sndP    = (int*)alloc((size_t)EPAD*4);
  unsigned* csrE = (unsigned*)alloc((size_t)EPAD*4);
  float* sF      = (float*)alloc((size_t)NN*64*4);
  float* vF      = (float*)alloc((size_t)NN*192*4);
  float4* nodeP  = (float4*)alloc((size_t)NN*64*16);
  float4* aggP   = (float4*)alloc((size_t)NN*64*16);
  float* acc_out = (float*)alloc((size_t)NN*9*4);
  float* T       = (float*)alloc(512*4);
  float4* Twts   = (float4*)alloc((size_t)NLAYERS*(NT+1)*64*16);
  int* deg     = (int*)alloc((size_t)NN*4);
  int* rowptrP = (int*)alloc((size_t)(NN+1)*4);
  int* cursor  = (int*)alloc((size_t)NN*4);

  hipMemsetAsync(deg, 0, (size_t)NN*4, stream);
  hipMemsetAsync(csrE, 0xFF, (size_t)EPAD*4, stream);   // pads sort to row tail

  k_count<<<EE/256, 256, 0, stream>>>(ei, deg);
  k_scan <<<1, 1024, 0, stream>>>(deg, rowptrP, cursor);
  k_scatter <<<EE/256, 256, 0, stream>>>(ei, cursor, csrE);
  k_sortrows<<<NN/8, 512, 0, stream>>>(rowptrP, csrE);
  k_geom_slot<<<(EPAD+255)/256, 256, 0, stream>>>(pos, cell, Sij, ei, batch, csrE,
                                                  y1mP, sndP);
  k_tab<<<NLAYERS*(NT+1), 64, 0, stream>>>(Wr1, br1, Wr2, br2, Wr3, Twts);
  k_embed0<<<NN*64/256, 256, 0, stream>>>(species, W_embed, W_x, W_up_s, T,
                                          sF, vF, nodeP, acc_out);

  const int GATHER_BLOCKS = 8 * ((NPG + 7) / 8);   // 2504: graph = b%8 (XCD swizzle)
  for (int l = 0; l < NLAYERS; ++l) {
    k_gather<<<GATHER_BLOCKS, 512, 0, stream>>>(rowptrP, (const float4*)y1mP, sndP,
                                                nodeP, Twts + (size_t)l*(NT+1)*64, aggP);
    int has_next = (l < NLAYERS-1) ? 1 : 0;
    const float* Wus_n = W_up_s + (has_next ? (l+1)*4096 : l*4096);
    const float* Wuv_n = W_up_v + (has_next ? (l+1)*4096 : l*4096);
    k_post<<<2500, 512, 0, stream>>>(aggP, species, T, sF, vF,
                                     W_msg_s + l*4096, W_msg_v + l*4096,
                                     W_sc_s + l*32768, W_sc_v + l*32768,
                                     W_p_s + l*4096, W_p_v + l*4096,
                                     W_read + l*192, Wus_n, Wuv_n,
                                     nodeP, acc_out, has_next);
  }
  k_final<<<72, 256, 0, stream>>>(acc_out, out);
}

// Round 15
// 1026.420 us; speedup vs baseline: 1.0295x; 1.0295x over previous
//
#include <hip/hip_runtime.h>
#include <math.h>

#define NN 20000
#define GG 8
#define NPG 2500
#define EE 640000
#define EPAD 944000   // upper bound: E + 15*NN, per-node degree padded to mult of 16
#define NLAYERS 3
#define CUTR 6.0f
#define AVGN 32.0f
#define NBASIS 8
#define NT 4096       // radial-table intervals over r in [0,1]; 4097 entries/layer

// Hard per-wave LDS handoff (used only in k_sortrows now): drain the DS queue so
// prior ds ops are COMPLETE; sched_barrier pins the compiler.
#define LDS_HANDOFF() do { \
    asm volatile("s_waitcnt lgkmcnt(0)" ::: "memory"); \
    __builtin_amdgcn_sched_barrier(0); \
  } while (0)

__device__ __forceinline__ float silu_f(float x){ return x / (1.0f + __expf(-x)); }

// ---------------- CSR degree count ----------------
__global__ void k_count(const int* __restrict__ ei, int* __restrict__ deg)
{
  int e = blockIdx.x * 256 + threadIdx.x;
  if (e >= EE) return;
  atomicAdd(&deg[ei[EE + e]], 1);
}

// padded scan: each row's extent rounded up to multiple of 16 (tiles never cross nodes)
__global__ void k_scan(const int* __restrict__ deg, int* __restrict__ rowptrP,
                       int* __restrict__ cursor)
{
  __shared__ int buf[1024];
  __shared__ int carry;
  int tid = threadIdx.x;
  if (tid == 0) carry = 0;
  __syncthreads();
  for (int base = 0; base < NN; base += 1024) {
    int i = base + tid;
    int x = (i < NN) ? ((deg[i] + 15) & ~15) : 0;
    buf[tid] = x; __syncthreads();
    for (int off = 1; off < 1024; off <<= 1) {
      int t = (tid >= off) ? buf[tid - off] : 0;
      __syncthreads();
      buf[tid] += t;
      __syncthreads();
    }
    int incl = buf[tid];
    int c = carry;
    __syncthreads();
    if (i < NN) { rowptrP[i] = c + incl - x; cursor[i] = c + incl - x; }
    if (tid == 1023) carry = c + incl;
    __syncthreads();
  }
  if (tid == 0) rowptrP[NN] = carry;
}

// ---------------- scatter edge ids into padded CSR slots (perm nondeterministic) ----------------
__global__ void k_scatter(const int* __restrict__ ei, int* __restrict__ cursor,
                          unsigned* __restrict__ csrE)
{
  int e = blockIdx.x * 256 + threadIdx.x;
  if (e >= EE) return;
  int slot = atomicAdd(&cursor[ei[EE + e]], 1);
  csrE[slot] = (unsigned)e;
}

// ---------------- per-row sort by edge id -> DETERMINISTIC slot assignment ----------------
__global__ __launch_bounds__(512) void k_sortrows(const int* __restrict__ rowptrP,
                                                  unsigned* __restrict__ csrE)
{
  __shared__ unsigned buf[8*512];
  int w = threadIdx.x >> 6, lane = threadIdx.x & 63;
  unsigned* b = buf + w*512;
  int r = blockIdx.x*8 + w;
  int start = rowptrP[r], end = rowptrP[r+1];
  int P = end - start;
  if (P < 2 || P > 512) return;   // max padded degree << 512 for this input
  for (int i = lane; i < P; i += 64) b[i] = csrE[start + i];
  LDS_HANDOFF();                 // loads committed before pass-0 cross-lane reads
  for (int pass = 0; pass < P; ++pass) {
    int par = pass & 1;
    for (int i = lane; 2*i + par + 1 < P; i += 64) {
      int idx = 2*i + par;
      unsigned a = b[idx], c = b[idx+1];
      if (a > c) { b[idx] = c; b[idx+1] = a; }
    }
    LDS_HANDOFF();               // pass-p ops complete before pass-p+1 touches buf
  }
  for (int i = lane; i < P; i += 64) csrE[start + i] = b[i];
}

// ---------------- geometry per SLOT ----------------
// y1m.w encodes BOTH mask and table coordinate: w = mask ? min(r,1) : -1.
// Pads and zero-length edges get w = -1 (gather treats w<0 as mask 0).
__global__ void k_geom_slot(const float* __restrict__ pos, const float* __restrict__ cell,
                            const float* __restrict__ Sij, const int* __restrict__ ei,
                            const int* __restrict__ batch, const unsigned* __restrict__ csrE,
                            float* __restrict__ y1mP, int* __restrict__ sndP)
{
  int slot = blockIdx.x * 256 + threadIdx.x;
  if (slot >= EPAD) return;
  int e = (int)csrE[slot];
  if (e < 0) {
    ((float4*)y1mP)[slot] = make_float4(0.0f, 0.0f, 0.0f, -1.0f);
    sndP[slot] = 0;
    return;
  }
  int snd = ei[e], rcv = ei[EE + e];
  int g = batch[snd];
  float s0 = Sij[e*3+0], s1 = Sij[e*3+1], s2_ = Sij[e*3+2];
  const float* cg = cell + g*9;
  float R[3];
  #pragma unroll
  for (int j = 0; j < 3; ++j) {
    float shift = s0*cg[0*3+j] + s1*cg[1*3+j] + s2_*cg[2*3+j];
    R[j] = (pos[rcv*3+j] - pos[snd*3+j] + shift) * (1.0f/CUTR);
  }
  float len = sqrtf(R[0]*R[0] + R[1]*R[1] + R[2]*R[2]);
  float safe = (len > 0.0f) ? len : 1.0f;
  float inv  = 1.0f / safe;
  const float sqrt3 = 1.7320508075688772f;
  float rq = (len > 0.0f) ? fminf(len, 1.0f) : -1.0f;   // table coord or mask=0
  ((float4*)y1mP)[slot] = make_float4(sqrt3*R[0]*inv, sqrt3*R[1]*inv, sqrt3*R[2]*inv, rq);
  sndP[slot] = snd;
}

// ---------------- radial table build: T[l][ip][c] = float4(paths 0..3), f32 ----------------
// wts = MLP(bess(r)*env(r)) depends on ONE scalar r; tabulate at 4097 points in f32.
// For r>=1 features are exactly 0 (env=0) -> F constant = MLP(0) = T[NT]; gather clamps.
// Lerp error ~ h^2|F''|/8 ~ 1e-5 relative (r10/r13/r14 measured: absmax 0.0).
__global__ __launch_bounds__(64) void k_tab(const float* __restrict__ Wr1, const float* __restrict__ br1,
                                            const float* __restrict__ Wr2, const float* __restrict__ br2,
                                            const float* __restrict__ Wr3, float4* __restrict__ Twts)
{
  __shared__ float h1s[64], h2s[64];
  int l  = blockIdx.x / (NT+1);
  int ip = blockIdx.x - l*(NT+1);
  int c  = threadIdx.x;
  float r  = (float)ip / (float)NT;
  float re = fmaxf(r, 1e-7f);
  float env = (r < 1.0f) ? (1.0f - 6.0f*r*r + 8.0f*r*r*r - 3.0f*r*r*r*r) : 0.0f;
  const float sqrt2 = 1.4142135623730951f;
  const float PI_F = 3.14159265358979323846f;
  float ef[NBASIS];
  #pragma unroll
  for (int n = 1; n <= NBASIS; ++n)
    ef[n-1] = sqrt2 * sinf(PI_F * (float)n * re) / re * env;
  float a = br1[l*64 + c];
  #pragma unroll
  for (int k = 0; k < NBASIS; ++k) a += ef[k] * Wr1[l*512 + k*64 + c];
  h1s[c] = a / (1.0f + expf(-a));
  __syncthreads();
  float b = br2[l*64 + c];
  for (int k = 0; k < 64; ++k) b += h1s[k] * Wr2[l*4096 + k*64 + c];
  h2s[c] = b / (1.0f + expf(-b));
  __syncthreads();
  float acc0 = 0, acc1 = 0, acc2 = 0, acc3 = 0;
  for (int k = 0; k < 64; ++k) {
    float h = h2s[k];
    const float* wv = Wr3 + l*16384 + k*256;   // wts[:,p,c] = flat[p*64 + c]
    acc0 += h * wv[0*64 + c];
    acc1 += h * wv[1*64 + c];
    acc2 += h * wv[2*64 + c];
    acc3 += h * wv[3*64 + c];
  }
  Twts[(size_t)(l*(NT+1) + ip)*64 + c] = make_float4(acc0, acc1, acc2, acc3);
}

// ---------------- embed: s, nodeP (layer-0 up), xf table, v/acc_out zero-init ----------------
__global__ void k_embed0(const int* __restrict__ species, const float* __restrict__ W_embed,
                         const float* __restrict__ W_x, const float* __restrict__ Wus0,
                         float* __restrict__ T,
                         float* __restrict__ s, float* __restrict__ v,
                         float4* __restrict__ nodeP, float* __restrict__ acc_out)
{
  if (blockIdx.x == 0) {        // xf table (512 entries), used by k_post every layer
    for (int t = threadIdx.x; t < 512; t += 256) {
      int sp = t >> 6, o = t & 63;
      float a = 0.0f;
      for (int k = 0; k < 64; ++k) a += W_embed[sp*64 + k] * W_x[k*64 + o];
      T[t] = a;
    }
  }
  int gid = blockIdx.x * 256 + threadIdx.x;
  if (gid >= NN * 64) return;
  int n = gid >> 6, c = gid & 63;
  int sp = species[n];
  s[gid] = W_embed[sp*64 + c];
  float up = 0.0f;              // layer-0 s_up inline (v=0 so v_up=0)
  for (int k = 0; k < 64; ++k) up += W_embed[sp*64 + k] * Wus0[k*64 + c];
  nodeP[gid] = make_float4(up, 0.0f, 0.0f, 0.0f);
  #pragma unroll
  for (int m = 0; m < 3; ++m) v[(n*3 + m)*64 + c] = 0.0f;
  if (c < 9) acc_out[n*9 + c] = 0.0f;
}

// ---------------- gather: table-lerp radial weights + message paths + aggregation ----------------
// GEOMETRY = r10's proven best (8-wave 512-thread blocks, 2504 blocks).
// r14 POST-MORTEM: deleting LDS staging with the 4-edge HOIST blew past the 128-VGPR
// cap -> scratch spill (WRITE 174MB). THIS ROUND: j-OUTER restructure — process ONE
// edge at a time (1 y1m + 1 snd + 4 np + 8 table loads per j). Loop-carried regs =
// 16 accumulators + addresses (~60-90 VGPR, no spill). Still zero DS ops / fences ->
// compiler pipelines j-iterations. Accumulation order per as[ctm]/av[ctm][m] is
// UNCHANGED (j=0..3 per tile, j/ctm interchange permutes only across distinct
// accumulators) -> bitwise-identical output (absmax 0.0).
// XCD swizzle: graph = blockIdx%8 -> graph's nodeP slice (2.5MB) lives in that XCD L2.
__global__ __launch_bounds__(512) void k_gather(
    const int* __restrict__ rowptrP,
    const float4* __restrict__ y1mP, const int* __restrict__ sndP,
    const float4* __restrict__ nodeP, const float4* __restrict__ Twts,
    float4* __restrict__ aggP)
{
  int tid = threadIdx.x;
  int w = tid >> 6, lane = tid & 63;
  int n16 = lane & 15, quad = lane >> 4;
  // XCD swizzle: graph = blockIdx%8, node-within-graph = (blockIdx/8)*8 + wave
  int g = blockIdx.x & 7, rr = (blockIdx.x >> 3)*8 + w;
  if (rr < NPG) {
  int r = g*NPG + rr;
  int start = rowptrP[r], end = rowptrP[r+1];
  float as[4] = {0,0,0,0};
  float av[4][3] = {{0,0,0},{0,0,0},{0,0,0},{0,0,0}};
  const float inv_sqrt3 = 0.5773502691896258f;

  for (int e0 = start; e0 < end; e0 += 16) {
    int eq = e0 + quad*4;
    #pragma unroll
    for (int j = 0; j < 4; ++j) {
      // direct edge load (same addr across the quad's 16 lanes -> broadcast)
      float4 y = y1mP[eq + j];
      int sj = sndP[eq + j];
      float u = y.w;
      float mk = (u >= 0.0f) ? 1.0f : 0.0f;
      float ppos = fmaxf(u, 0.0f) * (float)NT;
      int idx = (int)ppos; if (idx > NT-1) idx = NT-1;
      float f = ppos - (float)idx;
      const float4* npb = nodeP + (size_t)sj*64 + n16;
      const float4* tpb = Twts + (size_t)idx*64 + n16;
      #pragma unroll
      for (int ctm = 0; ctm < 4; ++ctm) {
        float4 npv = npb[ctm*16];
        float4 t0 = tpb[ctm*16];
        float4 t1 = tpb[ctm*16 + 64];
        float4 wp;
        wp.x = mk*(t0.x + f*(t1.x - t0.x));
        wp.y = mk*(t0.y + f*(t1.y - t0.y));
        wp.z = mk*(t0.z + f*(t1.z - t0.z));
        wp.w = mk*(t0.w + f*(t1.w - t0.w));
        float dot = npv.y*y.x + npv.z*y.y + npv.w*y.z;
        float t2 = wp.z*npv.x;
        as[ctm]    += wp.x*npv.x + wp.y*dot*inv_sqrt3;
        av[ctm][0] += t2*y.x + wp.w*npv.y;
        av[ctm][1] += t2*y.y + wp.w*npv.z;
        av[ctm][2] += t2*y.z + wp.w*npv.w;
      }
    }
  }
  // cross-quad butterfly + write packed agg
  const float invavg = 1.0f / AVGN;
  #pragma unroll
  for (int ctm = 0; ctm < 4; ++ctm) {
    float v0 = as[ctm], v1 = av[ctm][0], v2 = av[ctm][1], v3 = av[ctm][2];
    v0 += __shfl_xor(v0, 16); v0 += __shfl_xor(v0, 32);
    v1 += __shfl_xor(v1, 16); v1 += __shfl_xor(v1, 32);
    v2 += __shfl_xor(v2, 16); v2 += __shfl_xor(v2, 32);
    v3 += __shfl_xor(v3, 16); v3 += __shfl_xor(v3, 32);
    if (quad == 0)
      aggP[(size_t)r*64 + ctm*16 + n16] =
          make_float4(v0*invavg, v1*invavg, v2*invavg, v3*invavg);
  }
  }  // rr < NPG
}

// ---------------- post: msg/sc/product + readout + NEXT layer's up-projection ----------------
// 1 node/wave, 32 KB LDS -> 4 blocks/CU (32 waves). L2-streamed weights.
// Block-uniform control flow -> real __syncthreads() at the three cross-lane handoffs.
__global__ __launch_bounds__(512) void k_post(
    const float4* __restrict__ aggP, const int* __restrict__ species,
    const float* __restrict__ T,
    float* __restrict__ s, float* __restrict__ v,
    const float* __restrict__ Wms, const float* __restrict__ Wmv,
    const float* __restrict__ Wscs, const float* __restrict__ Wscv,
    const float* __restrict__ Wps, const float* __restrict__ Wpv,
    const float* __restrict__ Wread,
    const float* __restrict__ Wus_n, const float* __restrict__ Wuv_n,
    float4* __restrict__ nodeP, float* __restrict__ acc_out, int has_next)
{
  __shared__ float lds[8*1024];
  int tid = threadIdx.x; int w = tid >> 6, c = tid & 63;
  float* asb = lds + w*1024;   // 64
  float* avb = asb + 64;       // 192
  float* sob = avb + 192;      // 64
  float* vob = sob + 64;       // 192
  float* tsb = vob + 192;      // 64
  float* tvb = tsb + 64;       // 192
  float* snb = tvb + 192;      // 64
  float* vnb = snb + 64;       // 192
  int n = blockIdx.x*8 + w;
  int sp = species[n];
  float4 ag = aggP[(size_t)n*64 + c];
  asb[c] = ag.x; avb[c] = ag.y; avb[64+c] = ag.z; avb[128+c] = ag.w;
  sob[c] = s[n*64 + c];
  #pragma unroll
  for (int m = 0; m < 3; ++m) vob[m*64 + c] = v[(n*3 + m)*64 + c];
  __syncthreads();             // phase-1 writes -> cross-lane reads
  float ms = 0, mv0 = 0, mv1 = 0, mv2 = 0;
  for (int k = 0; k < 64; ++k) {
    float wm = Wms[k*64 + c];
    ms  += asb[k]*wm;
    float wv = Wmv[k*64 + c];
    mv0 += avb[k]*wv; mv1 += avb[64+k]*wv; mv2 += avb[128+k]*wv;
  }
  float xf = T[sp*64 + c];
  tsb[c] = xf*ms; tvb[c] = xf*mv0; tvb[64+c] = xf*mv1; tvb[128+c] = xf*mv2;
  __syncthreads();             // phase-2 writes -> cross-lane reads
  const float* Wss = Wscs + sp*4096;
  const float* Wsv = Wscv + sp*4096;
  float sn_ = 0, vn0 = 0, vn1 = 0, vn2 = 0;
  for (int k = 0; k < 64; ++k) {
    float wp  = Wps[k*64 + c];  sn_ += tsb[k]*wp;
    float wsc = Wss[k*64 + c];  sn_ += sob[k]*wsc;
    float wpv = Wpv[k*64 + c];
    vn0 += tvb[k]*wpv; vn1 += tvb[64+k]*wpv; vn2 += tvb[128+k]*wpv;
    float wsv = Wsv[k*64 + c];
    vn0 += vob[k]*wsv; vn1 += vob[64+k]*wsv; vn2 += vob[128+k]*wsv;
  }
  s[n*64 + c] = sn_;
  v[(n*3+0)*64 + c] = vn0; v[(n*3+1)*64 + c] = vn1; v[(n*3+2)*64 + c] = vn2;
  snb[c] = sn_; vnb[c] = vn0; vnb[64+c] = vn1; vnb[128+c] = vn2;
  __syncthreads();             // phase-3 writes -> cross-lane reads
  if (c < 9) {                         // readout, silu-accumulated across layers
    int o3 = c / 3, m = c % 3;
    const float* wr = Wread + o3*64;
    float a = 0.0f;
    for (int k = 0; k < 64; ++k) a += vnb[m*64 + k]*wr[k];
    acc_out[n*9 + c] += silu_f(a);
  }
  if (has_next) {                      // fused up-projection for next layer
    float su = 0, u0 = 0, u1 = 0, u2 = 0;
    for (int k = 0; k < 64; ++k) {
      float wu = Wus_n[k*64 + c]; su += snb[k]*wu;
      float wv = Wuv_n[k*64 + c];
      u0 += vnb[k]*wv; u1 += vnb[64+k]*wv; u2 += vnb[128+k]*wv;
    }
    nodeP[(size_t)n*64 + c] = make_float4(su, u0, u1, u2);
  }
}

// ---------------- final graph reduction ----------------
__global__ void k_final(const float* __restrict__ acc_out, float* __restrict__ out)
{
  __shared__ float red[256];
  int g = blockIdx.x / 9, j = blockIdx.x % 9;
  int tid = threadIdx.x;
  float a = 0.0f;
  for (int n = g*NPG + tid; n < (g + 1)*NPG; n += 256) a += acc_out[n*9 + j];
  red[tid] = a; __syncthreads();
  for (int off = 128; off > 0; off >>= 1) {
    if (tid < off) red[tid] += red[tid + off];
    __syncthreads();
  }
  if (tid == 0) out[g*9 + j] = red[0];
}

extern "C" void kernel_launch(void* const* d_in, const int* in_sizes, int n_in,
                              void* d_out, int out_size, void* d_ws, size_t ws_size,
                              hipStream_t stream)
{
  const float* pos     = (const float*)d_in[0];
  const float* cell    = (const float*)d_in[1];
  const float* Sij     = (const float*)d_in[2];
  const float* W_embed = (const float*)d_in[3];
  const float* W_x     = (const float*)d_in[4];
  const float* W_up_s  = (const float*)d_in[5];
  const float* W_up_v  = (const float*)d_in[6];
  const float* Wr1     = (const float*)d_in[7];
  const float* br1     = (const float*)d_in[8];
  const float* Wr2     = (const float*)d_in[9];
  const float* br2     = (const float*)d_in[10];
  const float* Wr3     = (const float*)d_in[11];
  const float* W_msg_s = (const float*)d_in[12];
  const float* W_msg_v = (const float*)d_in[13];
  const float* W_sc_s  = (const float*)d_in[14];
  const float* W_sc_v  = (const float*)d_in[15];
  const float* W_p_s   = (const float*)d_in[16];
  const float* W_p_v   = (const float*)d_in[17];
  const float* W_read  = (const float*)d_in[18];
  const int*   ei      = (const int*)d_in[19];
  const int*   batch   = (const int*)d_in[20];
  const int*   species = (const int*)d_in[21];
  float* out = (float*)d_out;

  char* ws = (char*)d_ws;
  size_t off = 0;
  auto alloc = [&](size_t bytes) -> void* {
    void* p = ws + off;
    off += (bytes + 255) & ~(size_t)255;
    return p;
  };
  float* y1mP    = (float*)alloc((size_t)EPAD*4*4);
  int*   sndP    = (int*)alloc((size_t)EPAD*4);
  unsigned* csrE = (unsigned*)alloc((size_t)EPAD*4);
  float* sF      = (float*)alloc((size_t)NN*64*4);
  float* vF      = (float*)alloc((size_t)NN*192*4);
  float4* nodeP  = (float4*)alloc((size_t)NN*64*16);
  float4* aggP   = (float4*)alloc((size_t)NN*64*16);
  float* acc_out = (float*)alloc((size_t)NN*9*4);
  float* T       = (float*)alloc(512*4);
  float4* Twts   = (float4*)alloc((size_t)NLAYERS*(NT+1)*64*16);
  int* deg     = (int*)alloc((size_t)NN*4);
  int* rowptrP = (int*)alloc((size_t)(NN+1)*4);
  int* cursor  = (int*)alloc((size_t)NN*4);

  hipMemsetAsync(deg, 0, (size_t)NN*4, stream);
  hipMemsetAsync(csrE, 0xFF, (size_t)EPAD*4, stream);   // pads sort to row tail

  k_count<<<EE/256, 256, 0, stream>>>(ei, deg);
  k_scan <<<1, 1024, 0, stream>>>(deg, rowptrP, cursor);
  k_scatter <<<EE/256, 256, 0, stream>>>(ei, cursor, csrE);
  k_sortrows<<<NN/8, 512, 0, stream>>>(rowptrP, csrE);
  k_geom_slot<<<(EPAD+255)/256, 256, 0, stream>>>(pos, cell, Sij, ei, batch, csrE,
                                                  y1mP, sndP);
  k_tab<<<NLAYERS*(NT+1), 64, 0, stream>>>(Wr1, br1, Wr2, br2, Wr3, Twts);
  k_embed0<<<NN*64/256, 256, 0, stream>>>(species, W_embed, W_x, W_up_s, T,
                                          sF, vF, nodeP, acc_out);

  const int GATHER_BLOCKS = 8 * ((NPG + 7) / 8);   // 2504: graph = b%8 (XCD swizzle)
  for (int l = 0; l < NLAYERS; ++l) {
    k_gather<<<GATHER_BLOCKS, 512, 0, stream>>>(rowptrP, (const float4*)y1mP, sndP,
                                                nodeP, Twts + (size_t)l*(NT+1)*64, aggP);
    int has_next = (l < NLAYERS-1) ? 1 : 0;
    const float* Wus_n = W_up_s + (has_next ? (l+1)*4096 : l*4096);
    const float* Wuv_n = W_up_v + (has_next ? (l+1)*4096 : l*4096);
    k_post<<<2500, 512, 0, stream>>>(aggP, species, T, sF, vF,
                                     W_msg_s + l*4096, W_msg_v + l*4096,
                                     W_sc_s + l*32768, W_sc_v + l*32768,
                                     W_p_s + l*4096, W_p_v + l*4096,
                                     W_read + l*192, Wus_n, Wuv_n,
                                     nodeP, acc_out, has_next);
  }
  k_final<<<72, 256, 0, stream>>>(acc_out, out);
}

// Round 16
// 912.116 us; speedup vs baseline: 1.1585x; 1.1253x over previous
//
#include <hip/hip_runtime.h>
#include <math.h>

#define NN 20000
#define GG 8
#define NPG 2500
#define EE 640000
#define EPAD 944000   // upper bound: E + 15*NN, per-node degree padded to mult of 16
#define NLAYERS 3
#define CUTR 6.0f
#define AVGN 32.0f
#define NBASIS 8
#define NT 4096       // radial-table intervals over r in [0,1]; 4097 entries/layer

// Hard per-wave LDS handoff: drain the DS queue so ALL prior ds ops (writes AND reads)
// are COMPLETE before anything after it executes; sched_barrier pins the compiler.
#define LDS_HANDOFF() do { \
    asm volatile("s_waitcnt lgkmcnt(0)" ::: "memory"); \
    __builtin_amdgcn_sched_barrier(0); \
  } while (0)

__device__ __forceinline__ float silu_f(float x){ return x / (1.0f + __expf(-x)); }

// ---------------- CSR degree count ----------------
__global__ void k_count(const int* __restrict__ ei, int* __restrict__ deg)
{
  int e = blockIdx.x * 256 + threadIdx.x;
  if (e >= EE) return;
  atomicAdd(&deg[ei[EE + e]], 1);
}

// padded scan: each row's extent rounded up to multiple of 16 (tiles never cross nodes)
__global__ void k_scan(const int* __restrict__ deg, int* __restrict__ rowptrP,
                       int* __restrict__ cursor)
{
  __shared__ int buf[1024];
  __shared__ int carry;
  int tid = threadIdx.x;
  if (tid == 0) carry = 0;
  __syncthreads();
  for (int base = 0; base < NN; base += 1024) {
    int i = base + tid;
    int x = (i < NN) ? ((deg[i] + 15) & ~15) : 0;
    buf[tid] = x; __syncthreads();
    for (int off = 1; off < 1024; off <<= 1) {
      int t = (tid >= off) ? buf[tid - off] : 0;
      __syncthreads();
      buf[tid] += t;
      __syncthreads();
    }
    int incl = buf[tid];
    int c = carry;
    __syncthreads();
    if (i < NN) { rowptrP[i] = c + incl - x; cursor[i] = c + incl - x; }
    if (tid == 1023) carry = c + incl;
    __syncthreads();
  }
  if (tid == 0) rowptrP[NN] = carry;
}

// ---------------- scatter edge ids into padded CSR slots (perm nondeterministic) ----------------
__global__ void k_scatter(const int* __restrict__ ei, int* __restrict__ cursor,
                          unsigned* __restrict__ csrE)
{
  int e = blockIdx.x * 256 + threadIdx.x;
  if (e >= EE) return;
  int slot = atomicAdd(&cursor[ei[EE + e]], 1);
  csrE[slot] = (unsigned)e;
}

// ---------------- per-row sort by edge id -> DETERMINISTIC slot assignment ----------------
__global__ __launch_bounds__(512) void k_sortrows(const int* __restrict__ rowptrP,
                                                  unsigned* __restrict__ csrE)
{
  __shared__ unsigned buf[8*512];
  int w = threadIdx.x >> 6, lane = threadIdx.x & 63;
  unsigned* b = buf + w*512;
  int r = blockIdx.x*8 + w;
  int start = rowptrP[r], end = rowptrP[r+1];
  int P = end - start;
  if (P < 2 || P > 512) return;   // max padded degree << 512 for this input
  for (int i = lane; i < P; i += 64) b[i] = csrE[start + i];
  LDS_HANDOFF();                 // loads committed before pass-0 cross-lane reads
  for (int pass = 0; pass < P; ++pass) {
    int par = pass & 1;
    for (int i = lane; 2*i + par + 1 < P; i += 64) {
      int idx = 2*i + par;
      unsigned a = b[idx], c = b[idx+1];
      if (a > c) { b[idx] = c; b[idx+1] = a; }
    }
    LDS_HANDOFF();               // pass-p ops complete before pass-p+1 touches buf
  }
  for (int i = lane; i < P; i += 64) csrE[start + i] = b[i];
}

// ---------------- geometry per SLOT ----------------
// y1m.w encodes BOTH mask and table coordinate: w = mask ? min(r,1) : -1.
// Pads and zero-length edges get w = -1 (gather treats w<0 as mask 0).
__global__ void k_geom_slot(const float* __restrict__ pos, const float* __restrict__ cell,
                            const float* __restrict__ Sij, const int* __restrict__ ei,
                            const int* __restrict__ batch, const unsigned* __restrict__ csrE,
                            float* __restrict__ y1mP, int* __restrict__ sndP)
{
  int slot = blockIdx.x * 256 + threadIdx.x;
  if (slot >= EPAD) return;
  int e = (int)csrE[slot];
  if (e < 0) {
    ((float4*)y1mP)[slot] = make_float4(0.0f, 0.0f, 0.0f, -1.0f);
    sndP[slot] = 0;
    return;
  }
  int snd = ei[e], rcv = ei[EE + e];
  int g = batch[snd];
  float s0 = Sij[e*3+0], s1 = Sij[e*3+1], s2_ = Sij[e*3+2];
  const float* cg = cell + g*9;
  float R[3];
  #pragma unroll
  for (int j = 0; j < 3; ++j) {
    float shift = s0*cg[0*3+j] + s1*cg[1*3+j] + s2_*cg[2*3+j];
    R[j] = (pos[rcv*3+j] - pos[snd*3+j] + shift) * (1.0f/CUTR);
  }
  float len = sqrtf(R[0]*R[0] + R[1]*R[1] + R[2]*R[2]);
  float safe = (len > 0.0f) ? len : 1.0f;
  float inv  = 1.0f / safe;
  const float sqrt3 = 1.7320508075688772f;
  float rq = (len > 0.0f) ? fminf(len, 1.0f) : -1.0f;   // table coord or mask=0
  ((float4*)y1mP)[slot] = make_float4(sqrt3*R[0]*inv, sqrt3*R[1]*inv, sqrt3*R[2]*inv, rq);
  sndP[slot] = snd;
}

// ---------------- radial table build: T[l][ip][c] = float4(paths 0..3), f32 ----------------
// wts = MLP(bess(r)*env(r)) depends on ONE scalar r; tabulate at 4097 points in f32.
// For r>=1 features are exactly 0 (env=0) -> F constant = MLP(0) = T[NT]; gather clamps.
// Lerp error ~ h^2|F''|/8 ~ 1e-5 relative (r10 measured: absmax 0.0).
__global__ __launch_bounds__(64) void k_tab(const float* __restrict__ Wr1, const float* __restrict__ br1,
                                            const float* __restrict__ Wr2, const float* __restrict__ br2,
                                            const float* __restrict__ Wr3, float4* __restrict__ Twts)
{
  __shared__ float h1s[64], h2s[64];
  int l  = blockIdx.x / (NT+1);
  int ip = blockIdx.x - l*(NT+1);
  int c  = threadIdx.x;
  float r  = (float)ip / (float)NT;
  float re = fmaxf(r, 1e-7f);
  float env = (r < 1.0f) ? (1.0f - 6.0f*r*r + 8.0f*r*r*r - 3.0f*r*r*r*r) : 0.0f;
  const float sqrt2 = 1.4142135623730951f;
  const float PI_F = 3.14159265358979323846f;
  float ef[NBASIS];
  #pragma unroll
  for (int n = 1; n <= NBASIS; ++n)
    ef[n-1] = sqrt2 * sinf(PI_F * (float)n * re) / re * env;
  float a = br1[l*64 + c];
  #pragma unroll
  for (int k = 0; k < NBASIS; ++k) a += ef[k] * Wr1[l*512 + k*64 + c];
  h1s[c] = a / (1.0f + expf(-a));
  __syncthreads();
  float b = br2[l*64 + c];
  for (int k = 0; k < 64; ++k) b += h1s[k] * Wr2[l*4096 + k*64 + c];
  h2s[c] = b / (1.0f + expf(-b));
  __syncthreads();
  float acc0 = 0, acc1 = 0, acc2 = 0, acc3 = 0;
  for (int k = 0; k < 64; ++k) {
    float h = h2s[k];
    const float* wv = Wr3 + l*16384 + k*256;   // wts[:,p,c] = flat[p*64 + c]
    acc0 += h * wv[0*64 + c];
    acc1 += h * wv[1*64 + c];
    acc2 += h * wv[2*64 + c];
    acc3 += h * wv[3*64 + c];
  }
  Twts[(size_t)(l*(NT+1) + ip)*64 + c] = make_float4(acc0, acc1, acc2, acc3);
}

// ---------------- embed: s, nodeP (layer-0 up), xf table, v/acc_out zero-init ----------------
__global__ void k_embed0(const int* __restrict__ species, const float* __restrict__ W_embed,
                         const float* __restrict__ W_x, const float* __restrict__ Wus0,
                         float* __restrict__ T,
                         float* __restrict__ s, float* __restrict__ v,
                         float4* __restrict__ nodeP, float* __restrict__ acc_out)
{
  if (blockIdx.x == 0) {        // xf table (512 entries), used by k_post every layer
    for (int t = threadIdx.x; t < 512; t += 256) {
      int sp = t >> 6, o = t & 63;
      float a = 0.0f;
      for (int k = 0; k < 64; ++k) a += W_embed[sp*64 + k] * W_x[k*64 + o];
      T[t] = a;
    }
  }
  int gid = blockIdx.x * 256 + threadIdx.x;
  if (gid >= NN * 64) return;
  int n = gid >> 6, c = gid & 63;
  int sp = species[n];
  s[gid] = W_embed[sp*64 + c];
  float up = 0.0f;              // layer-0 s_up inline (v=0 so v_up=0)
  for (int k = 0; k < 64; ++k) up += W_embed[sp*64 + k] * Wus0[k*64 + c];
  nodeP[gid] = make_float4(up, 0.0f, 0.0f, 0.0f);
  #pragma unroll
  for (int m = 0; m < 3; ++m) v[(n*3 + m)*64 + c] = 0.0f;
  if (c < 9) acc_out[n*9 + c] = 0.0f;
}

// ---------------- gather: table-lerp radial weights + message paths + aggregation ----------------
// BEST VERIFIED CONFIG (r10: 918us total, k_gather 119us/layer, absmax 0.0).
// 2504 blocks x 8 waves, one row per wave, LDS staging + hard fences. Subsequent
// experiments all regressed: 1-wave blocks (r12 spill 222us / r13 dispatch-limited
// 133us), fence-free direct loads (r14 hoist-spill 160us, r15 j-outer-spill 151us).
// The tiny LDS staging is LOAD-BEARING for register pressure: it keeps the live set
// under the 128-VGPR cliff that every fence-free variant fell off.
// XCD swizzle: graph = blockIdx%8 -> graph's nodeP slice (2.5MB) lives in that XCD L2.
__global__ __launch_bounds__(512, 2) void k_gather(
    const int* __restrict__ rowptrP,
    const float4* __restrict__ y1mP, const int* __restrict__ sndP,
    const float4* __restrict__ nodeP, const float4* __restrict__ Twts,
    float4* __restrict__ aggP)
{
  __shared__ float4 ymAll[8*16];               // per-wave y1m tile (w = rq)
  __shared__ int sndAll[8*16];                 // per-wave snd tile
  int tid = threadIdx.x;
  int w = tid >> 6, lane = tid & 63;
  int n16 = lane & 15, quad = lane >> 4;
  float4* ym = ymAll + w*16;
  int* sndL = sndAll + w*16;
  // XCD swizzle: graph = blockIdx%8, node-within-graph = (blockIdx/8)*8 + wave
  int g = blockIdx.x & 7, rr = (blockIdx.x >> 3)*8 + w;
  if (rr < NPG) {
  int r = g*NPG + rr;
  int start = rowptrP[r], end = rowptrP[r+1];
  float as[4] = {0,0,0,0};
  float av[4][3] = {{0,0,0},{0,0,0},{0,0,0},{0,0,0}};
  const float inv_sqrt3 = 0.5773502691896258f;

  for (int e0 = start; e0 < end; e0 += 16) {
    // stage edge meta in per-wave LDS (prior tile's reads drained at tile end)
    if (quad == 1) ym[n16] = y1mP[e0 + n16];
    if (quad == 2) sndL[n16] = sndP[e0 + n16];
    LDS_HANDOFF();               // RAW: staging writes complete before cross-lane reads
    // hoist this quad's 4 edges: y1, mask, table idx/frac
    float4 yj[4]; float mkj[4], fracj[4]; int idxj[4];
    #pragma unroll
    for (int j = 0; j < 4; ++j) {
      float4 y = ym[quad*4 + j];
      yj[j] = y;
      float u = y.w;
      mkj[j] = (u >= 0.0f) ? 1.0f : 0.0f;
      float ppos = fmaxf(u, 0.0f) * (float)NT;
      int idx = (int)ppos; if (idx > NT-1) idx = NT-1;
      idxj[j] = idx;
      fracj[j] = ppos - (float)idx;
    }
    // prefetch sender rows for the whole tile (latency hidden under table loads)
    float4 np[4][4];
    #pragma unroll
    for (int ctm = 0; ctm < 4; ++ctm)
      #pragma unroll
      for (int j = 0; j < 4; ++j)
        np[ctm][j] = nodeP[(size_t)sndL[quad*4 + j]*64 + ctm*16 + n16];
    // message paths: wts from table lerp (coalesced: 16 lanes x consecutive float4)
    #pragma unroll
    for (int ctm = 0; ctm < 4; ++ctm) {
      #pragma unroll
      for (int j = 0; j < 4; ++j) {
        const float4* tp = Twts + (size_t)idxj[j]*64 + ctm*16 + n16;
        float4 t0 = tp[0];
        float4 t1 = tp[64];
        float f = fracj[j], mk = mkj[j];
        float4 wp;
        wp.x = mk*(t0.x + f*(t1.x - t0.x));
        wp.y = mk*(t0.y + f*(t1.y - t0.y));
        wp.z = mk*(t0.z + f*(t1.z - t0.z));
        wp.w = mk*(t0.w + f*(t1.w - t0.w));
        float4 y = yj[j];
        float4 npv = np[ctm][j];
        float dot = npv.y*y.x + npv.z*y.y + npv.w*y.z;
        float t2 = wp.z*npv.x;
        as[ctm]    += wp.x*npv.x + wp.y*dot*inv_sqrt3;
        av[ctm][0] += t2*y.x + wp.w*npv.y;
        av[ctm][1] += t2*y.y + wp.w*npv.z;
        av[ctm][2] += t2*y.z + wp.w*npv.w;
      }
    }
    LDS_HANDOFF();               // WAR: ym reads complete before next tile's staging
  }
  // cross-quad butterfly + write packed agg
  const float invavg = 1.0f / AVGN;
  #pragma unroll
  for (int ctm = 0; ctm < 4; ++ctm) {
    float v0 = as[ctm], v1 = av[ctm][0], v2 = av[ctm][1], v3 = av[ctm][2];
    v0 += __shfl_xor(v0, 16); v0 += __shfl_xor(v0, 32);
    v1 += __shfl_xor(v1, 16); v1 += __shfl_xor(v1, 32);
    v2 += __shfl_xor(v2, 16); v2 += __shfl_xor(v2, 32);
    v3 += __shfl_xor(v3, 16); v3 += __shfl_xor(v3, 32);
    if (quad == 0)
      aggP[(size_t)r*64 + ctm*16 + n16] =
          make_float4(v0*invavg, v1*invavg, v2*invavg, v3*invavg);
  }
  }  // rr < NPG
}

// ---------------- post: msg/sc/product + readout + NEXT layer's up-projection ----------------
// 1 node/wave, 32 KB LDS -> 4 blocks/CU (32 waves). L2-streamed weights.
// Block-uniform control flow -> real __syncthreads() at the three cross-lane handoffs.
__global__ __launch_bounds__(512) void k_post(
    const float4* __restrict__ aggP, const int* __restrict__ species,
    const float* __restrict__ T,
    float* __restrict__ s, float* __restrict__ v,
    const float* __restrict__ Wms, const float* __restrict__ Wmv,
    const float* __restrict__ Wscs, const float* __restrict__ Wscv,
    const float* __restrict__ Wps, const float* __restrict__ Wpv,
    const float* __restrict__ Wread,
    const float* __restrict__ Wus_n, const float* __restrict__ Wuv_n,
    float4* __restrict__ nodeP, float* __restrict__ acc_out, int has_next)
{
  __shared__ float lds[8*1024];
  int tid = threadIdx.x; int w = tid >> 6, c = tid & 63;
  float* asb = lds + w*1024;   // 64
  float* avb = asb + 64;       // 192
  float* sob = avb + 192;      // 64
  float* vob = sob + 64;       // 192
  float* tsb = vob + 192;      // 64
  float* tvb = tsb + 64;       // 192
  float* snb = tvb + 192;      // 64
  float* vnb = snb + 64;       // 192
  int n = blockIdx.x*8 + w;
  int sp = species[n];
  float4 ag = aggP[(size_t)n*64 + c];
  asb[c] = ag.x; avb[c] = ag.y; avb[64+c] = ag.z; avb[128+c] = ag.w;
  sob[c] = s[n*64 + c];
  #pragma unroll
  for (int m = 0; m < 3; ++m) vob[m*64 + c] = v[(n*3 + m)*64 + c];
  __syncthreads();             // phase-1 writes -> cross-lane reads
  float ms = 0, mv0 = 0, mv1 = 0, mv2 = 0;
  for (int k = 0; k < 64; ++k) {
    float wm = Wms[k*64 + c];
    ms  += asb[k]*wm;
    float wv = Wmv[k*64 + c];
    mv0 += avb[k]*wv; mv1 += avb[64+k]*wv; mv2 += avb[128+k]*wv;
  }
  float xf = T[sp*64 + c];
  tsb[c] = xf*ms; tvb[c] = xf*mv0; tvb[64+c] = xf*mv1; tvb[128+c] = xf*mv2;
  __syncthreads();             // phase-2 writes -> cross-lane reads
  const float* Wss = Wscs + sp*4096;
  const float* Wsv = Wscv + sp*4096;
  float sn_ = 0, vn0 = 0, vn1 = 0, vn2 = 0;
  for (int k = 0; k < 64; ++k) {
    float wp  = Wps[k*64 + c];  sn_ += tsb[k]*wp;
    float wsc = Wss[k*64 + c];  sn_ += sob[k]*wsc;
    float wpv = Wpv[k*64 + c];
    vn0 += tvb[k]*wpv; vn1 += tvb[64+k]*wpv; vn2 += tvb[128+k]*wpv;
    float wsv = Wsv[k*64 + c];
    vn0 += vob[k]*wsv; vn1 += vob[64+k]*wsv; vn2 += vob[128+k]*wsv;
  }
  s[n*64 + c] = sn_;
  v[(n*3+0)*64 + c] = vn0; v[(n*3+1)*64 + c] = vn1; v[(n*3+2)*64 + c] = vn2;
  snb[c] = sn_; vnb[c] = vn0; vnb[64+c] = vn1; vnb[128+c] = vn2;
  __syncthreads();             // phase-3 writes -> cross-lane reads
  if (c < 9) {                         // readout, silu-accumulated across layers
    int o3 = c / 3, m = c % 3;
    const float* wr = Wread + o3*64;
    float a = 0.0f;
    for (int k = 0; k < 64; ++k) a += vnb[m*64 + k]*wr[k];
    acc_out[n*9 + c] += silu_f(a);
  }
  if (has_next) {                      // fused up-projection for next layer
    float su = 0, u0 = 0, u1 = 0, u2 = 0;
    for (int k = 0; k < 64; ++k) {
      float wu = Wus_n[k*64 + c]; su += snb[k]*wu;
      float wv = Wuv_n[k*64 + c];
      u0 += vnb[k]*wv; u1 += vnb[64+k]*wv; u2 += vnb[128+k]*wv;
    }
    nodeP[(size_t)n*64 + c] = make_float4(su, u0, u1, u2);
  }
}

// ---------------- final graph reduction ----------------
__global__ void k_final(const float* __restrict__ acc_out, float* __restrict__ out)
{
  __shared__ float red[256];
  int g = blockIdx.x / 9, j = blockIdx.x % 9;
  int tid = threadIdx.x;
  float a = 0.0f;
  for (int n = g*NPG + tid; n < (g + 1)*NPG; n += 256) a += acc_out[n*9 + j];
  red[tid] = a; __syncthreads();
  for (int off = 128; off > 0; off >>= 1) {
    if (tid < off) red[tid] += red[tid + off];
    __syncthreads();
  }
  if (tid == 0) out[g*9 + j] = red[0];
}

extern "C" void kernel_launch(void* const* d_in, const int* in_sizes, int n_in,
                              void* d_out, int out_size, void* d_ws, size_t ws_size,
                              hipStream_t stream)
{
  const float* pos     = (const float*)d_in[0];
  const float* cell    = (const float*)d_in[1];
  const float* Sij     = (const float*)d_in[2];
  const float* W_embed = (const float*)d_in[3];
  const float* W_x     = (const float*)d_in[4];
  const float* W_up_s  = (const float*)d_in[5];
  const float* W_up_v  = (const float*)d_in[6];
  const float* Wr1     = (const float*)d_in[7];
  const float* br1     = (const float*)d_in[8];
  const float* Wr2     = (const float*)d_in[9];
  const float* br2     = (const float*)d_in[10];
  const float* Wr3     = (const float*)d_in[11];
  const float* W_msg_s = (const float*)d_in[12];
  const float* W_msg_v = (const float*)d_in[13];
  const float* W_sc_s  = (const float*)d_in[14];
  const float* W_sc_v  = (const float*)d_in[15];
  const float* W_p_s   = (const float*)d_in[16];
  const float* W_p_v   = (const float*)d_in[17];
  const float* W_read  = (const float*)d_in[18];
  const int*   ei      = (const int*)d_in[19];
  const int*   batch   = (const int*)d_in[20];
  const int*   species = (const int*)d_in[21];
  float* out = (float*)d_out;

  char* ws = (char*)d_ws;
  size_t off = 0;
  auto alloc = [&](size_t bytes) -> void* {
    void* p = ws + off;
    off += (bytes + 255) & ~(size_t)255;
    return p;
  };
  float* y1mP    = (float*)alloc((size_t)EPAD*4*4);
  int*   sndP    = (int*)alloc((size_t)EPAD*4);
  unsigned* csrE = (unsigned*)alloc((size_t)EPAD*4);
  float* sF      = (float*)alloc((size_t)NN*64*4);
  float* vF      = (float*)alloc((size_t)NN*192*4);
  float4* nodeP  = (float4*)alloc((size_t)NN*64*16);
  float4* aggP   = (float4*)alloc((size_t)NN*64*16);
  float* acc_out = (float*)alloc((size_t)NN*9*4);
  float* T       = (float*)alloc(512*4);
  float4* Twts   = (float4*)alloc((size_t)NLAYERS*(NT+1)*64*16);
  int* deg     = (int*)alloc((size_t)NN*4);
  int* rowptrP = (int*)alloc((size_t)(NN+1)*4);
  int* cursor  = (int*)alloc((size_t)NN*4);

  hipMemsetAsync(deg, 0, (size_t)NN*4, stream);
  hipMemsetAsync(csrE, 0xFF, (size_t)EPAD*4, stream);   // pads sort to row tail

  k_count<<<EE/256, 256, 0, stream>>>(ei, deg);
  k_scan <<<1, 1024, 0, stream>>>(deg, rowptrP, cursor);
  k_scatter <<<EE/256, 256, 0, stream>>>(ei, cursor, csrE);
  k_sortrows<<<NN/8, 512, 0, stream>>>(rowptrP, csrE);
  k_geom_slot<<<(EPAD+255)/256, 256, 0, stream>>>(pos, cell, Sij, ei, batch, csrE,
                                                  y1mP, sndP);
  k_tab<<<NLAYERS*(NT+1), 64, 0, stream>>>(Wr1, br1, Wr2, br2, Wr3, Twts);
  k_embed0<<<NN*64/256, 256, 0, stream>>>(species, W_embed, W_x, W_up_s, T,
                                          sF, vF, nodeP, acc_out);

  const int GATHER_BLOCKS = 8 * ((NPG + 7) / 8);   // 2504: graph = b%8 (XCD swizzle)
  for (int l = 0; l < NLAYERS; ++l) {
    k_gather<<<GATHER_BLOCKS, 512, 0, stream>>>(rowptrP, (const float4*)y1mP, sndP,
                                                nodeP, Twts + (size_t)l*(NT+1)*64, aggP);
    int has_next = (l < NLAYERS-1) ? 1 : 0;
    const float* Wus_n = W_up_s + (has_next ? (l+1)*4096 : l*4096);
    const float* Wuv_n = W_up_v + (has_next ? (l+1)*4096 : l*4096);
    k_post<<<2500, 512, 0, stream>>>(aggP, species, T, sF, vF,
                                     W_msg_s + l*4096, W_msg_v + l*4096,
                                     W_sc_s + l*32768, W_sc_v + l*32768,
                                     W_p_s + l*4096, W_p_v + l*4096,
                                     W_read + l*192, Wus_n, Wuv_n,
                                     nodeP, acc_out, has_next);
  }
  k_final<<<72, 256, 0, stream>>>(acc_out, out);
}